// Round 6
// baseline (156.836 us; speedup 1.0000x reference)
//
#include <hip/hip_runtime.h>

#define NIN  128
#define NOUT 128
#define NN   256   // N
#define BB   4     // batch

typedef float f4 __attribute__((ext_vector_type(4)));

// Single fused kernel. Grid = 2048 blocks: (b,o) x 4 row-chunks of 64 rows
// (8 blocks/CU). 256 threads.
//
// Phase 1 (4x redundant per bo, cost is trivial): thread = (j-quad tq, channel
//   group g of 32). 32 coalesced 16B loads of node + 256 FMAs -> LDS partials,
//   tree-reduce to su[2][256]. node slice (128 KB/b) is L2-resident.
// Phase 2: out[b,o,i,j] = adj[b,i,j] * (i==j ? ui[j] : uj[j]); 16 independent
//   1 KiB/wave row stores per thread. Write-roofline bound.
__global__ __launch_bounds__(256) void nodeconv_one(
    const float* __restrict__ adj,   // [B,1,N,N]
    const float* __restrict__ node,  // [B,NIN,N]
    const float* __restrict__ Wi,    // [NOUT,NIN]
    const float* __restrict__ Wj,    // [NOUT,NIN]
    float* __restrict__ out)         // [B,NOUT,N,N]
{
    __shared__ f4    part[2][4][64];  // [sel][group][j-quad]  8 KiB
    __shared__ float su[2][NN];       // [sel][j]  (0=ui, 1=uj)  2 KiB

    const int blk = blockIdx.x;
    const int bo  = blk >> 2;         // b*NOUT + o
    const int qc  = blk & 3;          // 64-row chunk
    const int b   = bo >> 7;
    const int o   = bo & (NOUT - 1);
    const int t   = threadIdx.x;

    // ---- Phase 1: u{i,j}[j] = sum_c W{i,j}[o,c] * node[b,c,j] ----
    {
        const int tq = t & 63;        // j-quad: columns 4*tq..4*tq+3
        const int g  = t >> 6;        // channel group: c in [32g, 32g+32)
        const f4*    np4 = (const f4*)node + ((size_t)b * NIN + g * 32) * 64 + tq;
        const float* wi  = Wi + o * NIN + g * 32;   // block-uniform -> scalar loads
        const float* wj  = Wj + o * NIN + g * 32;
        f4 ai = {0.f, 0.f, 0.f, 0.f};
        f4 aj = {0.f, 0.f, 0.f, 0.f};
        #pragma unroll 8
        for (int c = 0; c < 32; ++c) {
            const f4 n = np4[(size_t)c * 64];       // 16B/lane, coalesced row
            ai += wi[c] * n;
            aj += wj[c] * n;
        }
        part[0][g][tq] = ai;
        part[1][g][tq] = aj;
    }
    __syncthreads();
    if (t < 128) {
        const int tq  = t & 63;
        const int sel = t >> 6;
        const f4 s = part[sel][0][tq] + part[sel][1][tq]
                   + part[sel][2][tq] + part[sel][3][tq];
        *(f4*)&su[sel][tq << 2] = s;
    }
    __syncthreads();

    // ---- Phase 2: stream 64 rows of the 256x256 tile ----
    const int jb = (t & 63) << 2;     // base column (fixed per thread)
    const int rr = t >> 6;            // 0..3

    const f4 vj = *(const f4*)&su[1][jb];   // hoisted off-diagonal values

    const float* adjb = adj + (size_t)b * (NN * NN);
    float*       outp = out + (size_t)bo * (NN * NN);

    const int i0 = (qc << 6) + rr;    // rows i0, i0+4, ..., i0+60
    #pragma unroll
    for (int r = 0; r < 16; ++r) {
        const int i = i0 + (r << 2);
        const float s_ii = su[0][i];                  // wave-uniform LDS broadcast
        const f4 a = *(const f4*)&adjb[i * NN + jb];
        f4 v;
        v.x = (i == jb + 0) ? s_ii : vj.x;
        v.y = (i == jb + 1) ? s_ii : vj.y;
        v.z = (i == jb + 2) ? s_ii : vj.z;
        v.w = (i == jb + 3) ? s_ii : vj.w;
        *(f4*)&outp[i * NN + jb] = a * v;             // 1 KiB contiguous per wave
    }
}

extern "C" void kernel_launch(void* const* d_in, const int* in_sizes, int n_in,
                              void* d_out, int out_size, void* d_ws, size_t ws_size,
                              hipStream_t stream) {
    const float* adj  = (const float*)d_in[0];  // [4,1,256,256]
    const float* node = (const float*)d_in[1];  // [4,128,256]
    const float* Wi   = (const float*)d_in[2];  // [128,128]
    const float* Wj   = (const float*)d_in[3];  // [128,128]
    float* out = (float*)d_out;                 // [4,128,256,256]

    nodeconv_one<<<dim3(BB * NOUT * 4), dim3(256), 0, stream>>>(adj, node, Wi, Wj, out);
}